// Round 10
// baseline (2778.429 us; speedup 1.0000x reference)
//
#include <hip/hip_runtime.h>

#define LOWV (-10000.0f)
#define NBLK 256
typedef unsigned long long u64;
typedef __attribute__((ext_vector_type(2))) float f32x2;

__device__ __forceinline__ float sigf(float x){ return 1.0f/(1.0f+expf(-x)); }
__device__ __forceinline__ unsigned fkey(float f){
    unsigned u = __float_as_uint(f);
    return (u & 0x80000000u) ? ~u : (u | 0x80000000u);
}
__device__ __forceinline__ float funkey(unsigned k){
    unsigned u = (k & 0x80000000u) ? (k ^ 0x80000000u) : ~k;
    return __uint_as_float(u);
}
__device__ __forceinline__ int   aload_i (const int* p){ return __hip_atomic_load(p, __ATOMIC_RELAXED, __HIP_MEMORY_SCOPE_AGENT); }
__device__ __forceinline__ float aload_f (const float* p){ return __hip_atomic_load(p, __ATOMIC_RELAXED, __HIP_MEMORY_SCOPE_AGENT); }
__device__ __forceinline__ u64   aload_u64(const u64* p){ return __hip_atomic_load(p, __ATOMIC_RELAXED, __HIP_MEMORY_SCOPE_AGENT); }
__device__ __forceinline__ void  astore_f(float* p, float v){ __hip_atomic_store(p, v, __ATOMIC_RELAXED, __HIP_MEMORY_SCOPE_AGENT); }
__device__ __forceinline__ void  astore_u64(u64* p, u64 v){ __hip_atomic_store(p, v, __ATOMIC_RELAXED, __HIP_MEMORY_SCOPE_AGENT); }
__device__ __forceinline__ float bload(const float* p){ return aload_f(p); }
__device__ __forceinline__ void  bstore(float* p, float v){ astore_f(p, v); }
__device__ __forceinline__ float2 bload2(const float* p){
    union { u64 u; float2 f; } c; c.u = aload_u64((const u64*)p); return c.f;
}
__device__ __forceinline__ void bstore2(float* p, float2 v){
    union { u64 u; float2 f; } c; c.f = v; astore_u64((u64*)p, c.u);
}

// pipelined MALL-coherent loads (bypass L1+L2): issue batches, counted vmcnt waits
#define GLD2(dst, p, OFF) asm volatile("global_load_dwordx2 %0, %1, off offset:" OFF " sc0 sc1" : "=v"(dst) : "v"(p))
#define GLD1(dst, p)      asm volatile("global_load_dword %0, %1, off sc0 sc1" : "=v"(dst) : "v"(p))
#define ISSUE8(B, p) do{ GLD2(B[0],p,"0"); GLD2(B[1],p,"512"); GLD2(B[2],p,"1024"); GLD2(B[3],p,"1536"); \
                         GLD2(B[4],p,"2048"); GLD2(B[5],p,"2560"); GLD2(B[6],p,"3072"); GLD2(B[7],p,"3584"); }while(0)
#define WAITV(N) do{ asm volatile("s_waitcnt vmcnt(" #N ")" ::: "memory"); __builtin_amdgcn_sched_barrier(0); }while(0)

// ---------- transposes: WT[3072][640] = [Wh|Wpred]^T, WoutT[1024][512], WencT[512][1024] ----------
__global__ __launch_bounds__(256) void k_tr(const float* __restrict__ Wh, const float* __restrict__ Wpred,
        const float* __restrict__ Wout, const float* __restrict__ Wenc,
        float* __restrict__ WT, float* __restrict__ WoutT, float* __restrict__ WencT,
        int* __restrict__ cntZ){
    if (blockIdx.x == 0){ for (int i = threadIdx.x; i < 544; i += 256) cntZ[i] = 0; }
    __shared__ float t[64][65];
    int b = blockIdx.x;
    const float* in; float* outp; int R, C, tr, tc, doff;
    if (b < 400)      { in=Wh;    outp=WT;    R=640;  C=2560; tr=b/40;        tc=b%40;        doff=0; }
    else if (b < 480) { b-=400; in=Wpred; outp=WT;    R=640;  C=512;  tr=b/8;  tc=b%8;  doff=2560; }
    else if (b < 608) { b-=480; in=Wout;  outp=WoutT; R=512;  C=1024; tr=b>>4; tc=b&15; doff=0; }
    else              { b-=608; in=Wenc;  outp=WencT; R=1024; C=512;  tr=b/8;  tc=b%8;  doff=0; }
    int tx = threadIdx.x & 63, ty0 = threadIdx.x >> 6;
    #pragma unroll
    for (int i = 0; i < 16; ++i){
        int row = i*4 + ty0;
        t[row][tx] = in[(size_t)(tr*64 + row)*C + tc*64 + tx];
    }
    __syncthreads();
    #pragma unroll
    for (int i = 0; i < 16; ++i){
        int row = i*4 + ty0;
        outp[(size_t)(doff + tc*64 + row)*R + tr*64 + tx] = t[tx][row];
    }
}

// ---------- EWi4[v*640+j] = float4 gates of E@Wi + bi + bh ----------
__global__ __launch_bounds__(256) void k_ewi(const float* __restrict__ E, const float* __restrict__ Wi,
        const float* __restrict__ bi, const float* __restrict__ bh, float4* __restrict__ EWi4){
    int tid = threadIdx.x, lane = tid & 63, wvv = tid >> 6;
    int vb = blockIdx.x / 10, jb = blockIdx.x % 10;   // 1280 blocks
    int j = jb*64 + lane;
    int v0 = vb*8 + wvv*2;
    float acc[2][4];
    #pragma unroll
    for (int i=0;i<2;++i)
        #pragma unroll
        for (int g=0;g<4;++g) acc[i][g] = 0.f;
    for (int k0 = 0; k0 < 512; k0 += 4){
        float ev[2][4];
        #pragma unroll
        for (int i=0;i<2;++i) *(float4*)ev[i] = *(const float4*)(E + (size_t)(v0+i)*512 + k0);
        #pragma unroll
        for (int kk=0;kk<4;++kk){
            const float* wr = Wi + (size_t)(k0+kk)*2560 + j;
            float w0 = wr[0], w1 = wr[640], w2 = wr[1280], w3 = wr[1920];
            #pragma unroll
            for (int i=0;i<2;++i){
                acc[i][0] += ev[i][kk]*w0; acc[i][1] += ev[i][kk]*w1;
                acc[i][2] += ev[i][kk]*w2; acc[i][3] += ev[i][kk]*w3;
            }
        }
    }
    float b0 = bi[j] + bh[j], b1 = bi[640+j] + bh[640+j];
    float b2 = bi[1280+j] + bh[1280+j], b3 = bi[1920+j] + bh[1920+j];
    #pragma unroll
    for (int i=0;i<2;++i)
        EWi4[(size_t)(v0+i)*640 + j] = make_float4(acc[i][0]+b0, acc[i][1]+b1, acc[i][2]+b2, acc[i][3]+b3);
}

// ---------- persistent decode kernel: 256 blocks x 512 threads, fence-free, pipelined loads ----------
__global__ __launch_bounds__(512, 2) void mega(
    const float* __restrict__ enc, const int* __restrict__ lens, const float* __restrict__ bj,
    const float* __restrict__ WT, const float* __restrict__ WoutT, const float* __restrict__ WencT,
    const float4* __restrict__ EWi4,
    float* __restrict__ hT, float* __restrict__ encPT, float* __restrict__ jointT, float* __restrict__ gT,
    u64* __restrict__ packedP, float* __restrict__ sumexpP,
    int* __restrict__ cntZ, float* __restrict__ out)
{
    __shared__ float sW[12*640];
    __shared__ __align__(16) float sXP[12*8*128];
    __shared__ float sB[8*512];
    __shared__ float sWe[6*1024];
    __shared__ float sBJ12[12];
    __shared__ int sAct[128], sEncT[128], sNEm[128], sLen[128];
    __shared__ int sTok[128], sUpd[128], sAdv[128];

    const int bid = blockIdx.x, tid = threadIdx.x, lane = tid & 63, wv = tid >> 6;
    int ep = 0;
    float creg = 0.f, scReg = 0.f;

    auto gsync = [&](){
        asm volatile("s_waitcnt vmcnt(0)" ::: "memory");
        __syncthreads();
        ++ep;
        if (tid == 0){
            __hip_atomic_fetch_add(&cntZ[(bid & 15)*16], 1, __ATOMIC_RELAXED, __HIP_MEMORY_SCOPE_AGENT);
            if (bid < 16){
                while (__hip_atomic_load(&cntZ[bid*16], __ATOMIC_RELAXED, __HIP_MEMORY_SCOPE_AGENT) < ep*16)
                    __builtin_amdgcn_s_sleep(2);
                __hip_atomic_fetch_add(&cntZ[256], 1, __ATOMIC_RELAXED, __HIP_MEMORY_SCOPE_AGENT);
            }
            if (bid == 0){
                while (__hip_atomic_load(&cntZ[256], __ATOMIC_RELAXED, __HIP_MEMORY_SCOPE_AGENT) < ep*16)
                    __builtin_amdgcn_s_sleep(2);
                #pragma unroll
                for (int i = 0; i < 16; ++i)
                    __hip_atomic_store(&cntZ[272 + i*16], ep, __ATOMIC_RELAXED, __HIP_MEMORY_SCOPE_AGENT);
            } else {
                while (__hip_atomic_load(&cntZ[272 + (bid & 15)*16], __ATOMIC_RELAXED, __HIP_MEMORY_SCOPE_AGENT) < ep)
                    __builtin_amdgcn_s_sleep(4);
            }
        }
        __syncthreads();
    };

    // ---- weight staging (cached; read-only stays L2-hot) ----
    for (int i = tid; i < 7680; i += 512){
        int c = i / 640, k = i - c*640;
        sW[k*12 + c] = WT[(size_t)(bid*12 + c)*640 + k];
    }
    if (bid < 128){
        for (int i = tid; i < 4096; i += 512){
            int k = i >> 3, c = i & 7;
            sB[k*8 + c] = WoutT[(size_t)(bid*8 + c)*512 + k];
        }
    }
    const int ec0 = (bid >= 160 && bid < 246) ? (bid-160)*6 : -1;
    const int nc  = (ec0 >= 0) ? ((512 - ec0) < 6 ? (512 - ec0) : 6) : 0;
    if (ec0 >= 0){
        for (int i = tid; i < 6144; i += 512){
            int cc = i >> 10, k = i & 1023;
            if (cc < nc) sWe[i] = WencT[(size_t)(ec0+cc)*1024 + k];
        }
    }
    if (tid < 12){
        int col = bid*12 + tid;
        sBJ12[tid] = (col >= 2560) ? bj[col - 2560] : 0.f;
    }
    if (tid < 128){
        sAct[tid] = 1; sEncT[tid] = 0; sNEm[tid] = 0; sLen[tid] = lens[tid];
    }
    __syncthreads();

    // ---- prologue ----
    for (int i = tid; i < 24; i += 512){
        int idx = bid*24 + i;
        astore_u64(&packedP[(size_t)idx*8], 0ull);
        astore_f(&sumexpP[(size_t)idx*16], 0.f);
    }
    if (bid < 160){
        int j = bid*4 + (tid >> 7), r = tid & 127;
        float4 e0 = EWi4[j];
        float c0v = sigf(e0.x)*tanhf(e0.z);
        creg = c0v;
        bstore(&hT[(size_t)j*128 + r], tanhf(c0v)*sigf(e0.w));
    }
    if (ec0 >= 0){
        for (int r = wv; r < 128; r += 8){
            const float* er = enc + (size_t)r*160*1024;   // frame 0
            float a[6] = {0,0,0,0,0,0};
            int k4 = lane*4;
            #pragma unroll
            for (int i = 0; i < 4; ++i){
                int k = i*256 + k4;
                float4 ev = *(const float4*)(er + k);
                for (int cc = 0; cc < nc; ++cc){
                    float4 w4 = *(const float4*)(sWe + cc*1024 + k);
                    a[cc] += ev.x*w4.x + ev.y*w4.y + ev.z*w4.z + ev.w*w4.w;
                }
            }
            for (int cc = 0; cc < nc; ++cc){
                #pragma unroll
                for (int off = 32; off; off >>= 1) a[cc] += __shfl_xor(a[cc], off, 64);
                if (lane == 0) bstore(&encPT[(size_t)(ec0+cc)*128 + r], a[cc]);
            }
        }
    }
    gsync();   // B0

#define FMA12(BUF, KB) do{ _Pragma("unroll") for (int kk=0;kk<8;++kk){ \
    f32x2 h2 = BUF[kk]; const float* wr = sW + (size_t)((KB)+kk)*12; \
    float4 wa=*(const float4*)(wr); float4 wb=*(const float4*)(wr+4); float4 wc=*(const float4*)(wr+8); \
    acc[0]+=h2[0]*wa.x;  acc[1]+=h2[1]*wa.x;  acc[2]+=h2[0]*wa.y;  acc[3]+=h2[1]*wa.y; \
    acc[4]+=h2[0]*wa.z;  acc[5]+=h2[1]*wa.z;  acc[6]+=h2[0]*wa.w;  acc[7]+=h2[1]*wa.w; \
    acc[8]+=h2[0]*wb.x;  acc[9]+=h2[1]*wb.x;  acc[10]+=h2[0]*wb.y; acc[11]+=h2[1]*wb.y; \
    acc[12]+=h2[0]*wb.z; acc[13]+=h2[1]*wb.z; acc[14]+=h2[0]*wb.w; acc[15]+=h2[1]*wb.w; \
    acc[16]+=h2[0]*wc.x; acc[17]+=h2[1]*wc.x; acc[18]+=h2[0]*wc.y; acc[19]+=h2[1]*wc.y; \
    acc[20]+=h2[0]*wc.z; acc[21]+=h2[1]*wc.z; acc[22]+=h2[0]*wc.w; acc[23]+=h2[1]*wc.w; } }while(0)

#define FMA8C(BUF, KB) do{ _Pragma("unroll") for (int kk=0;kk<8;++kk){ \
    f32x2 j2 = BUF[kk]; const float* wr = sB + (size_t)((KB)+kk)*8; \
    float4 wa=*(const float4*)(wr); float4 wb=*(const float4*)(wr+4); \
    acc[0]+=j2[0]*wa.x;  acc[1]+=j2[1]*wa.x;  acc[2]+=j2[0]*wa.y;  acc[3]+=j2[1]*wa.y; \
    acc[4]+=j2[0]*wa.z;  acc[5]+=j2[1]*wa.z;  acc[6]+=j2[0]*wa.w;  acc[7]+=j2[1]*wa.w; \
    acc[8]+=j2[0]*wb.x;  acc[9]+=j2[1]*wb.x;  acc[10]+=j2[0]*wb.y; acc[11]+=j2[1]*wb.y; \
    acc[12]+=j2[0]*wb.z; acc[13]+=j2[1]*wb.z; acc[14]+=j2[0]*wb.w; acc[15]+=j2[1]*wb.w; } }while(0)

    for (int s = 0; s < 48; ++s){
        const int p = s & 1, w = 1 - p;
        const float* hp = hT + (size_t)p*81920;

        // ===== P1: flat GEMV 3072 cols, 12 cols/block; ping-pong 8-batches, counted vmcnt =====
        {
            float acc[24];
            #pragma unroll
            for (int c = 0; c < 24; ++c) acc[c] = 0.f;
            const float* hc = hp + 2*lane;
            const float* bp = hc + (size_t)(wv*80)*128;
            f32x2 hA[8], hB[8];
            asm volatile("s_waitcnt vmcnt(0)" ::: "memory");   // protect counted waits
            ISSUE8(hA, bp);
            #pragma unroll
            for (int b = 0; b < 5; ++b){
                ISSUE8(hB, bp + 1024);
                WAITV(8);
                FMA12(hA, wv*80 + b*16);
                bp += 2048;
                if (b < 4){
                    ISSUE8(hA, bp);
                    WAITV(8);
                } else {
                    WAITV(0);
                }
                FMA12(hB, wv*80 + b*16 + 8);
            }
            float2* sX2 = (float2*)sXP;
            #pragma unroll
            for (int c = 0; c < 12; ++c)
                sX2[c*512 + wv*64 + lane] = make_float2(acc[2*c], acc[2*c+1]);
        }
        __syncthreads();
        {
            float2* sX2 = (float2*)sXP;
            for (int u = tid; u < 768; u += 512){
                int c = u >> 6, l = u & 63;
                float vx = 0.f, vy = 0.f;
                #pragma unroll
                for (int ks = 0; ks < 8; ++ks){
                    float2 q = sX2[c*512 + ks*64 + l];
                    vx += q.x; vy += q.y;
                }
                int col = bid*12 + c;
                if (col < 2560){
                    bstore2(&gT[(size_t)col*128 + 2*l], make_float2(vx, vy));
                } else {
                    int cj = col - 2560;
                    float2 e = bload2(&encPT[(size_t)cj*128 + 2*l]);
                    float bjv = sBJ12[c];
                    bstore2(&jointT[(size_t)cj*128 + 2*l],
                            make_float2(tanhf(vx + e.x + bjv), tanhf(vy + e.y + bjv)));
                }
            }
        }
        gsync();   // B1

        // ===== P2: logits 8 cols/block (blocks 0..127); ping-pong batches =====
        if (bid < 128){
            float acc[16];
            #pragma unroll
            for (int c = 0; c < 16; ++c) acc[c] = 0.f;
            const float* jc = jointT + 2*lane;
            const float* bp = jc + (size_t)(wv*64)*128;
            f32x2 jA[8], jB[8];
            asm volatile("s_waitcnt vmcnt(0)" ::: "memory");
            ISSUE8(jA, bp);
            #pragma unroll
            for (int b = 0; b < 4; ++b){
                ISSUE8(jB, bp + 1024);
                WAITV(8);
                FMA8C(jA, wv*64 + b*16);
                bp += 2048;
                if (b < 3){
                    ISSUE8(jA, bp);
                    WAITV(8);
                } else {
                    WAITV(0);
                }
                FMA8C(jB, wv*64 + b*16 + 8);
            }
            float2* sX2 = (float2*)sXP;
            #pragma unroll
            for (int c = 0; c < 8; ++c)
                sX2[c*512 + wv*64 + lane] = make_float2(acc[2*c], acc[2*c+1]);
            __syncthreads();
            u64 key[2]; float exv[2];
            #pragma unroll
            for (int i = 0; i < 2; ++i){
                int u = tid + i*512;
                int c = u >> 7, r2 = u & 127;
                float lg = 0.f;
                #pragma unroll
                for (int ks = 0; ks < 8; ++ks) lg += sXP[c*1024 + ks*128 + r2];
                exv[i] = expf(lg);
                int col = bid*8 + c;
                bool force = sNEm[r2] >= 2;
                int idx; float va;
                if (col == 0){ idx = 1024; va = lg; }
                else { idx = col; va = force ? LOWV : lg; }
                key[i] = ((u64)fkey(va) << 32) | (unsigned)(2047 - idx);
            }
            __syncthreads();
            u64* kx = (u64*)sXP;
            float* exs = (float*)(kx + 1024);
            #pragma unroll
            for (int i = 0; i < 2; ++i){
                int u = tid + i*512;
                int c = u >> 7, r2 = u & 127;
                kx[c*128 + r2] = key[i];
                exs[c*128 + r2] = exv[i];
            }
            __syncthreads();
            if (tid < 128){
                u64 m = kx[tid]; float es = exs[tid];
                #pragma unroll
                for (int q = 1; q < 8; ++q){
                    u64 o = kx[q*128 + tid]; if (o > m) m = o;
                    es += exs[q*128 + tid];
                }
                atomicMax(&packedP[((size_t)s*128 + tid)*8], m);
                atomicAdd(&sumexpP[((size_t)s*128 + tid)*16], es);
            }
        }
        gsync();   // B2

        // ===== P3: tok gather + replicated state | LSTM pointwise | lazy enc-proj | scorer =====
        if (tid < 128){
            u64 pk = aload_u64(&packedP[((size_t)s*128 + tid)*8]);
            int tok = 2047 - (int)(unsigned)(pk & 0xffffffffu);
            int act = sAct[tid];
            int isb = (tok == 1024);
            sTok[tid] = tok;
            sUpd[tid] = act && !isb;
            int et = sEncT[tid], ne = sNEm[tid], act_n = act, adv = -1;
            if (act){
                et += isb;
                ne = isb ? 0 : ne + 1;
                act_n = (et < sLen[tid]) ? 1 : 0;
                if (isb && act_n) adv = et;
            }
            sAdv[tid] = adv;
            sAct[tid] = act_n; sEncT[tid] = et; sNEm[tid] = ne;
            if (bid == 255){
                int tok_out = 1024;
                if (act){
                    float val = funkey((unsigned)(pk >> 32));
                    float se = aload_f(&sumexpP[((size_t)s*128 + tid)*16]);
                    scReg += val - logf(se);
                    tok_out = (act_n || isb) ? tok : 1024;
                }
                out[(size_t)tid*48 + s] = (float)tok_out;
                if (s == 47) out[6144 + tid] = scReg;
            }
        }
        __syncthreads();
        if (bid < 160){
            int j = bid*4 + (tid >> 7), r = tid & 127;
            float g0, g1, g2, g3, hv;
            asm volatile("s_waitcnt vmcnt(0)" ::: "memory");
            GLD1(g0, &gT[(size_t)j*128 + r]);
            GLD1(g1, &gT[(size_t)(640 + j)*128 + r]);
            GLD1(g2, &gT[(size_t)(1280 + j)*128 + r]);
            GLD1(g3, &gT[(size_t)(1920 + j)*128 + r]);
            GLD1(hv, &hp[(size_t)j*128 + r]);
            WAITV(0);
            float h2;
            if (sUpd[r]){
                int tok = sTok[r];
                float4 ew = EWi4[(size_t)tok*640 + j];
                float cn = sigf(g1 + ew.y)*creg + sigf(g0 + ew.x)*tanhf(g2 + ew.z);
                h2 = tanhf(cn)*sigf(g3 + ew.w);
                creg = cn;
            } else {
                h2 = hv;
            }
            bstore(&hT[(size_t)w*81920 + (size_t)j*128 + r], h2);
        } else if (ec0 >= 0){
            for (int r = wv; r < 128; r += 8){
                int t = sAdv[r];
                if (t < 0) continue;
                const float* er = enc + ((size_t)r*160 + t)*1024;
                float a[6] = {0,0,0,0,0,0};
                int k4 = lane*4;
                #pragma unroll
                for (int i = 0; i < 4; ++i){
                    int k = i*256 + k4;
                    float4 ev = *(const float4*)(er + k);
                    for (int cc = 0; cc < nc; ++cc){
                        float4 w4 = *(const float4*)(sWe + cc*1024 + k);
                        a[cc] += ev.x*w4.x + ev.y*w4.y + ev.z*w4.z + ev.w*w4.w;
                    }
                }
                for (int cc = 0; cc < nc; ++cc){
                    #pragma unroll
                    for (int off = 32; off; off >>= 1) a[cc] += __shfl_xor(a[cc], off, 64);
                    if (lane == 0) bstore(&encPT[(size_t)(ec0+cc)*128 + r], a[cc]);
                }
            }
        }
        gsync();    // B3
    }
}

extern "C" void kernel_launch(void* const* d_in, const int* in_sizes, int n_in,
                              void* d_out, int out_size, void* d_ws, size_t ws_size,
                              hipStream_t stream) {
    const float* enc   = (const float*)d_in[0];
    const int*   lens  = (const int*)  d_in[1];
    const float* E     = (const float*)d_in[3];
    const float* Wi    = (const float*)d_in[4];
    const float* Wh    = (const float*)d_in[5];
    const float* bi    = (const float*)d_in[6];
    const float* bh    = (const float*)d_in[7];
    const float* Wenc  = (const float*)d_in[8];
    const float* Wpred = (const float*)d_in[9];
    const float* bj    = (const float*)d_in[10];
    const float* Wout  = (const float*)d_in[11];
    float* out = (float*)d_out;

    char* base = (char*)d_ws;
    size_t off = 0;
    auto carve = [&](size_t bytes) -> void* {
        void* pp = base + off;
        off += (bytes + 255) & ~(size_t)255;
        return pp;
    };
    float*  WT    = (float*)carve((size_t)3072*640*4);
    float*  WoutT = (float*)carve((size_t)1024*512*4);
    float*  WencT = (float*)carve((size_t)512*1024*4);
    float4* EWi4  = (float4*)carve((size_t)1024*640*16);
    float*  hT    = (float*)carve((size_t)2*640*128*4);
    float*  encPT = (float*)carve((size_t)512*128*4);
    float*  jointT= (float*)carve((size_t)512*128*4);
    float*  gT    = (float*)carve((size_t)2560*128*4);
    u64*    packedP = (u64*)carve((size_t)48*128*8*8);
    float*  sumexpP = (float*)carve((size_t)48*128*16*4);
    int*    cntZ  = (int*)carve(544*4);
    (void)ws_size; (void)in_sizes; (void)n_in; (void)out_size;

    k_tr <<<736,  256, 0, stream>>>(Wh, Wpred, Wout, Wenc, WT, WoutT, WencT, cntZ);
    k_ewi<<<1280, 256, 0, stream>>>(E, Wi, bi, bh, EWi4);
    mega <<<NBLK, 512, 0, stream>>>(enc, lens, bj, WT, WoutT, WencT, EWi4,
                                    hT, encPT, jointT, gT, packedP, sumexpP, cntZ, out);
}